// Round 1
// baseline (230.301 us; speedup 1.0000x reference)
//
#include <hip/hip_runtime.h>
#include <math.h>

// Problem constants (from reference)
#define NB 320
#define NAC 5
#define NH 26
#define NW 26
#define CHW (NH * NW)              // 676
#define KTOT (NAC * CHW)           // 3380
#define BSTRIDE (30 * CHW)         // 20280 floats per batch image
#define MAXB 50
#define CS 20
#define NMETA 20
#define DWROWS 64
#define DWDIM 1024

__constant__ float c_aw[5] = {1.3221f, 3.19275f, 5.05587f, 9.47112f, 11.2364f};
__constant__ float c_ah[5] = {1.73145f, 4.00944f, 8.09892f, 4.84053f, 10.0071f};

// ---------------------------------------------------------------------------
// Kernel 1: init marker map to -1 and zero the scalar output.
// ---------------------------------------------------------------------------
__global__ void init_k(int* __restrict__ marker, float* __restrict__ loss) {
    int id = blockIdx.x * blockDim.x + threadIdx.x;
    if (id < NB * KTOT) marker[id] = -1;
    if (id == 0) loss[0] = 0.0f;
}

// ---------------------------------------------------------------------------
// Kernel 2: scatter phase. One thread per (b, t) gt box. Winner for a cell is
// the LARGEST t (numpy last-write-wins), resolved via atomicMax.
// ---------------------------------------------------------------------------
__global__ void scatter_k(const float* __restrict__ target, int* __restrict__ marker) {
    int id = blockIdx.x * blockDim.x + threadIdx.x;
    if (id >= NB * MAXB) return;
    int b = id / MAXB;
    int t = id - b * MAXB;
    const float* g = target + b * (MAXB * 5) + t * 5;
    float g1 = g[1];
    if (g1 == 0.0f) return;  // invalid box -> dropped
    float gx = g1 * (float)NW;
    float gy = g[2] * (float)NH;
    float gw = g[3] * (float)NW;
    float gh = g[4] * (float)NH;
    // best anchor by anchor-space IoU (first max wins)
    float ga = gw * gh;
    int bn = 0;
    float best = -1.0f;
#pragma unroll
    for (int n = 0; n < 5; n++) {
        float inter = fminf(gw, c_aw[n]) * fminf(gh, c_ah[n]);
        float iou = inter / (ga + c_aw[n] * c_ah[n] - inter);
        if (iou > best) { best = iou; bn = n; }
    }
    int gi = (int)gx;  // trunc-toward-zero == astype(int32) for positives
    gi = min(max(gi, 0), NW - 1);
    int gj = (int)gy;
    gj = min(max(gj, 0), NH - 1);
    int fidx = ((b * NAC + bn) * NH + gj) * NW + gi;
    atomicMax(&marker[fidx], t);
}

// ---------------------------------------------------------------------------
// Kernel 3: main per-cell loss. Grid: (ceil(KTOT/256), NB). Each block stages
// its batch's 50 boxes in LDS (extents for the silence test + raw geometry
// for override targets), then each thread handles one cell.
// ---------------------------------------------------------------------------
__global__ __launch_bounds__(256) void main_k(const float* __restrict__ out,
                                              const float* __restrict__ target,
                                              const int* __restrict__ marker,
                                              float* __restrict__ loss) {
    // SoA box data: [0]=lox [1]=hix [2]=loy [3]=hiy [4]=area [5]=gx [6]=gy [7]=gw [8]=gh
    __shared__ float sb[9 * MAXB];
    __shared__ float sred[4];

    int b = blockIdx.y;
    int tid = threadIdx.x;
    if (tid < MAXB) {
        const float* g = target + b * (MAXB * 5) + tid * 5;
        float g1 = g[1];
        float gx = g1 * (float)NW;
        float gy = g[2] * (float)NH;
        float gw = g[3] * (float)NW;
        float gh = g[4] * (float)NH;
        float lox, hix, loy, hiy;
        if (g1 != 0.0f) {
            lox = gx - 0.5f * gw; hix = gx + 0.5f * gw;
            loy = gy - 0.5f * gh; hiy = gy + 0.5f * gh;
        } else {
            // invalid: make intersection impossible
            lox = 1e30f; hix = -1e30f; loy = 1e30f; hiy = -1e30f;
        }
        sb[0 * MAXB + tid] = lox;
        sb[1 * MAXB + tid] = hix;
        sb[2 * MAXB + tid] = loy;
        sb[3 * MAXB + tid] = hiy;
        sb[4 * MAXB + tid] = gw * gh;
        sb[5 * MAXB + tid] = gx;
        sb[6 * MAXB + tid] = gy;
        sb[7 * MAXB + tid] = gw;
        sb[8 * MAXB + tid] = gh;
    }
    __syncthreads();

    int k = blockIdx.x * blockDim.x + tid;
    float contrib = 0.0f;
    if (k < KTOT) {
        int a = k / CHW;
        int rem = k - a * CHW;
        int i = rem / NW;
        int j = rem - i * NW;
        const float* cell = out + (size_t)b * BSTRIDE + a * 6 * CHW + rem;
        float rx = cell[0 * CHW];
        float ry = cell[1 * CHW];
        float w  = cell[2 * CHW];
        float h  = cell[3 * CHW];
        float rc = cell[4 * CHW];
        float x = 1.0f / (1.0f + expf(-rx));
        float y = 1.0f / (1.0f + expf(-ry));
        float conf = 1.0f / (1.0f + expf(-rc));
        float aw = c_aw[a], ah = c_ah[a];
        float pw = expf(w) * aw;
        float ph = expf(h) * ah;
        float px = x + (float)j;
        float py = y + (float)i;
        float plox = px - 0.5f * pw, phix = px + 0.5f * pw;
        float ploy = py - 0.5f * ph, phiy = py + 0.5f * ph;
        float parea = pw * ph;

        int mk = marker[(size_t)b * KTOT + k];
        if (mk >= 0) {
            // overridden cell: recompute targets from the winning box
            float gx = sb[5 * MAXB + mk];
            float gy = sb[6 * MAXB + mk];
            float gw = sb[7 * MAXB + mk];
            float gh = sb[8 * MAXB + mk];
            float txv = gx - (float)j;      // gi_clipped == j for this cell
            float tyv = gy - (float)i;
            float twv = logf(gw / aw);
            float thv = logf(gh / ah);
            // iou_gt between gt box and predicted box at this cell
            float ix = fminf(phix, sb[1 * MAXB + mk]) - fmaxf(plox, sb[0 * MAXB + mk]);
            float iy = fminf(phiy, sb[3 * MAXB + mk]) - fmaxf(ploy, sb[2 * MAXB + mk]);
            float inter = (ix > 0.0f && iy > 0.0f) ? ix * iy : 0.0f;
            float iou = inter / (parea + sb[4 * MAXB + mk] - inter);
            float dx = x - txv, dy = y - tyv;
            float dw = w - twv, dh = h - thv;
            float dc = conf - iou;
            contrib = 0.5f * (dx * dx + dy * dy + dw * dw + dh * dh) + 2.5f * dc * dc;
            // class loss: softmax over the CS=20 images in this chunk
            int bs = b / CS;
            int cs = b - bs * CS;
            const float* cl = out + (size_t)(bs * CS) * BSTRIDE + (a * 6 + 5) * CHW + rem;
            float v[CS];
#pragma unroll
            for (int c2 = 0; c2 < CS; c2++) v[c2] = cl[(size_t)c2 * BSTRIDE];
            float m = v[0];
#pragma unroll
            for (int c2 = 1; c2 < CS; c2++) m = fmaxf(m, v[c2]);
            float s = 0.0f;
            float own = 0.0f;
#pragma unroll
            for (int c2 = 0; c2 < CS; c2++) {
                s += expf(v[c2] - m);
                if (c2 == cs) own = v[c2];
            }
            contrib += (m + logf(s)) - own;
        } else {
            // silence test: any gt box with IoU > 0.6 ?
            // iou > 0.6  <=>  inter > 0.375*(parea + barea)
            bool silent = false;
            for (int tb = 0; tb < MAXB; tb++) {
                float ix = fminf(phix, sb[1 * MAXB + tb]) - fmaxf(plox, sb[0 * MAXB + tb]);
                float iy = fminf(phiy, sb[3 * MAXB + tb]) - fmaxf(ploy, sb[2 * MAXB + tb]);
                if (ix > 0.0f && iy > 0.0f) {
                    float inter = ix * iy;
                    if (inter > 0.375f * (parea + sb[4 * MAXB + tb])) { silent = true; break; }
                }
            }
            float dx = x - 0.5f, dy = y - 0.5f;
            contrib = 0.5f * (dx * dx + dy * dy + w * w + h * h);
            if (!silent) contrib += 0.5f * conf * conf;
        }
    }

    // block reduction: wave shuffle then cross-wave via LDS
#pragma unroll
    for (int o = 32; o > 0; o >>= 1) contrib += __shfl_down(contrib, o, 64);
    int lane = tid & 63, wid = tid >> 6;
    if (lane == 0) sred[wid] = contrib;
    __syncthreads();
    if (tid == 0) {
        float bsum = sred[0] + sred[1] + sred[2] + sred[3];
        atomicAdd(loss, bsum);
    }
}

// ---------------------------------------------------------------------------
// Kernel 4: meta loss (same - different). Single block, 1024 threads, one
// thread per embedding dim. enews lives in global ws (80 KB static LDS would
// exceed the static limit).
// ---------------------------------------------------------------------------
__global__ __launch_bounds__(1024) void meta_k(const float* __restrict__ dw,
                                               const int* __restrict__ ids,
                                               float* __restrict__ enews,
                                               float* __restrict__ loss) {
    __shared__ int sids[DWROWS];
    __shared__ int scnt[NMETA];
    __shared__ float dmat[NMETA * NMETA];
    __shared__ float red[16];
    __shared__ float ddiff[NMETA];

    int d = threadIdx.x;
    if (d < DWROWS) sids[d] = ids[d];
    __syncthreads();

    if (d < NMETA) {
        int c = 0;
        for (int r = 0; r < DWROWS; r++) c += (sids[r] == d) ? 1 : 0;
        scnt[d] = c;
    }
    // per-class column sums: each thread owns column d (no races)
#pragma unroll
    for (int c = 0; c < NMETA; c++) enews[c * DWDIM + d] = 0.0f;
    for (int r = 0; r < DWROWS; r++) {
        enews[sids[r] * DWDIM + d] += dw[r * DWDIM + d];
    }
    __syncthreads();  // scnt visible
#pragma unroll
    for (int c = 0; c < NMETA; c++) {
        enews[c * DWDIM + d] *= 1.0f / fmaxf((float)scnt[c], 1.0f);
    }
    // same = sum ||dw_r - enews[id_r]||^2  (reads only own column -> no sync)
    float same = 0.0f;
    for (int r = 0; r < DWROWS; r++) {
        float df = dw[r * DWDIM + d] - enews[sids[r] * DWDIM + d];
        same += df * df;
    }
    __syncthreads();  // enews globally visible for the pair phase

    // pairwise distances: 400 pairs over 16 waves, 64-lane reductions
    int lane = d & 63, wid = d >> 6;
    for (int p = wid; p < NMETA * NMETA; p += 16) {
        int pi = p / NMETA;
        int pj = p - pi * NMETA;
        float s = 0.0f;
        if (pi != pj) {
            for (int q = lane; q < DWDIM; q += 64) {
                float df = enews[pi * DWDIM + q] - enews[pj * DWDIM + q];
                s += df * df;
            }
        }
#pragma unroll
        for (int o = 32; o > 0; o >>= 1) s += __shfl_down(s, o, 64);
        if (lane == 0) dmat[p] = s;
    }
    __syncthreads();

    if (d < NMETA) {
        bool present_i = scnt[d] > 0;
        float dmin = INFINITY;
        bool any = false;
        for (int j = 0; j < NMETA; j++) {
            if (j != d && present_i && scnt[j] > 0) {
                any = true;
                dmin = fminf(dmin, dmat[d * NMETA + j]);
            }
        }
        ddiff[d] = any ? dmin : 0.0f;
    }
    // reduce same across the block
#pragma unroll
    for (int o = 32; o > 0; o >>= 1) same += __shfl_down(same, o, 64);
    if (lane == 0) red[wid] = same;
    __syncthreads();
    if (d == 0) {
        float tot = 0.0f;
        for (int wv = 0; wv < 16; wv++) tot += red[wv];
        float diff = 0.0f;
        for (int i2 = 0; i2 < NMETA; i2++) diff += ddiff[i2];
        atomicAdd(loss, tot - diff);
    }
}

// ---------------------------------------------------------------------------
extern "C" void kernel_launch(void* const* d_in, const int* in_sizes, int n_in,
                              void* d_out, int out_size, void* d_ws, size_t ws_size,
                              hipStream_t stream) {
    const float* output = (const float*)d_in[0];   // (320, 30, 26, 26)
    const float* target = (const float*)d_in[1];   // (16, 20, 250) == (320, 50, 5)
    const float* dw     = (const float*)d_in[2];   // (1, 64, 1024)
    const int*   ids    = (const int*)d_in[3];     // (64,)
    float* loss = (float*)d_out;

    int* marker = (int*)d_ws;                              // NB*KTOT ints = 4.33 MB
    float* enews = (float*)((char*)d_ws + (size_t)NB * KTOT * sizeof(int));  // 80 KB

    int ncells = NB * KTOT;
    init_k<<<(ncells + 255) / 256, 256, 0, stream>>>(marker, loss);
    scatter_k<<<(NB * MAXB + 255) / 256, 256, 0, stream>>>(target, marker);
    dim3 grid((KTOT + 255) / 256, NB);
    main_k<<<grid, 256, 0, stream>>>(output, target, marker, loss);
    meta_k<<<1, 1024, 0, stream>>>(dw, ids, enews, loss);
}

// Round 2
// 155.141 us; speedup vs baseline: 1.4845x; 1.4845x over previous
//
#include <hip/hip_runtime.h>
#include <math.h>

// Problem constants (from reference)
#define NB 320
#define NAC 5
#define NH 26
#define NW 26
#define CHW (NH * NW)              // 676
#define KTOT (NAC * CHW)           // 3380
#define BSTRIDE (30 * CHW)         // 20280 floats per batch image
#define MAXB 50
#define CS 20
#define NMETA 20
#define DWROWS 64
#define DWDIM 1024

__constant__ float c_aw[5] = {1.3221f, 3.19275f, 5.05587f, 9.47112f, 11.2364f};
__constant__ float c_ah[5] = {1.73145f, 4.00944f, 8.09892f, 4.84053f, 10.0071f};

// ---------------------------------------------------------------------------
// Main per-cell loss. Grid: (14, 320). Each block stages its batch's 50 boxes
// (extents + geometry + target-cell fidx) in LDS; each thread handles one
// cell, fusing the scatter-winner match (max t == numpy last-write-wins) into
// the 50-box silence loop. No global marker map needed.
// ---------------------------------------------------------------------------
__global__ __launch_bounds__(256) void main_k(const float* __restrict__ out,
                                              const float* __restrict__ target,
                                              float* __restrict__ loss) {
    // SoA box data: [0]=lox [1]=hix [2]=loy [3]=hiy [4]=area [5]=gx [6]=gy [7]=gw [8]=gh
    __shared__ float sb[9 * MAXB];
    __shared__ int sfidx[MAXB];
    __shared__ float sred[4];

    int b = blockIdx.y;
    int tid = threadIdx.x;
    if (tid < MAXB) {
        const float* g = target + b * (MAXB * 5) + tid * 5;
        float g1 = g[1];
        float gx = g1 * (float)NW;
        float gy = g[2] * (float)NH;
        float gw = g[3] * (float)NW;
        float gh = g[4] * (float)NH;
        float lox, hix, loy, hiy, area;
        int fidx;
        if (g1 != 0.0f) {
            lox = gx - 0.5f * gw; hix = gx + 0.5f * gw;
            loy = gy - 0.5f * gh; hiy = gy + 0.5f * gh;
            area = gw * gh;
            // best anchor by anchor-space IoU (first max wins: strict >)
            int bn = 0;
            float best = -1.0f;
#pragma unroll
            for (int n = 0; n < 5; n++) {
                float inter = fminf(gw, c_aw[n]) * fminf(gh, c_ah[n]);
                float iou = inter / (area + c_aw[n] * c_ah[n] - inter);
                if (iou > best) { best = iou; bn = n; }
            }
            int gi = min(max((int)gx, 0), NW - 1);   // trunc == astype(int32), vals >= 0
            int gj = min(max((int)gy, 0), NH - 1);
            fidx = (bn * NH + gj) * NW + gi;         // within-batch cell id
        } else {
            // invalid: impossible extents, no match
            lox = 1e30f; hix = -1e30f; loy = 1e30f; hiy = -1e30f; area = 0.0f;
            fidx = -1;
        }
        sb[0 * MAXB + tid] = lox;
        sb[1 * MAXB + tid] = hix;
        sb[2 * MAXB + tid] = loy;
        sb[3 * MAXB + tid] = hiy;
        sb[4 * MAXB + tid] = area;
        sb[5 * MAXB + tid] = gx;
        sb[6 * MAXB + tid] = gy;
        sb[7 * MAXB + tid] = gw;
        sb[8 * MAXB + tid] = gh;
        sfidx[tid] = fidx;
    }
    __syncthreads();

    int k = blockIdx.x * blockDim.x + tid;
    float contrib = 0.0f;
    if (k < KTOT) {
        int a = k / CHW;
        int rem = k - a * CHW;
        int i = rem / NW;
        int j = rem - i * NW;
        const float* cell = out + (size_t)b * BSTRIDE + a * 6 * CHW + rem;
        float rx = cell[0 * CHW];
        float ry = cell[1 * CHW];
        float w  = cell[2 * CHW];
        float h  = cell[3 * CHW];
        float rc = cell[4 * CHW];
        float x = 1.0f / (1.0f + __expf(-rx));
        float y = 1.0f / (1.0f + __expf(-ry));
        float conf = 1.0f / (1.0f + __expf(-rc));
        float aw = c_aw[a], ah = c_ah[a];
        float pw = __expf(w) * aw;
        float ph = __expf(h) * ah;
        float px = x + (float)j;
        float py = y + (float)i;
        float plox = px - 0.5f * pw, phix = px + 0.5f * pw;
        float ploy = py - 0.5f * ph, phiy = py + 0.5f * ph;
        float parea = pw * ph;

        // fused loop: silence test (iou > 0.6 <=> inter > 0.375*(pa+ba))
        // + scatter-winner match (largest t wins = last-write-wins)
        bool silent = false;
        int mk = -1;
#pragma unroll 5
        for (int tb = 0; tb < MAXB; tb++) {
            float ix = fminf(phix, sb[1 * MAXB + tb]) - fmaxf(plox, sb[0 * MAXB + tb]);
            float iy = fminf(phiy, sb[3 * MAXB + tb]) - fmaxf(ploy, sb[2 * MAXB + tb]);
            float inter = fmaxf(ix, 0.0f) * fmaxf(iy, 0.0f);
            silent = silent || (inter > 0.375f * (parea + sb[4 * MAXB + tb]));
            mk = (k == sfidx[tb]) ? tb : mk;
        }

        if (mk >= 0) {
            // overridden cell: recompute targets from the winning box
            float gx = sb[5 * MAXB + mk];
            float gy = sb[6 * MAXB + mk];
            float gw = sb[7 * MAXB + mk];
            float gh = sb[8 * MAXB + mk];
            float txv = gx - (float)j;      // gi_clipped == j for this cell
            float tyv = gy - (float)i;
            float twv = __logf(gw / aw);
            float thv = __logf(gh / ah);
            float ix = fminf(phix, sb[1 * MAXB + mk]) - fmaxf(plox, sb[0 * MAXB + mk]);
            float iy = fminf(phiy, sb[3 * MAXB + mk]) - fmaxf(ploy, sb[2 * MAXB + mk]);
            float inter = fmaxf(ix, 0.0f) * fmaxf(iy, 0.0f);
            float iou = inter / (parea + sb[4 * MAXB + mk] - inter);
            float dx = x - txv, dy = y - tyv;
            float dwv = w - twv, dhv = h - thv;
            float dc = conf - iou;
            contrib = 0.5f * (dx * dx + dy * dy + dwv * dwv + dhv * dhv) + 2.5f * dc * dc;
            // class loss: log-softmax over the CS=20 images of this chunk
            int bs = b / CS;
            int cs = b - bs * CS;
            const float* cl = out + (size_t)(bs * CS) * BSTRIDE + (a * 6 + 5) * CHW + rem;
            float v[CS];
#pragma unroll
            for (int c2 = 0; c2 < CS; c2++) v[c2] = cl[(size_t)c2 * BSTRIDE];
            float m = v[0];
#pragma unroll
            for (int c2 = 1; c2 < CS; c2++) m = fmaxf(m, v[c2]);
            float s = 0.0f;
            float own = 0.0f;
#pragma unroll
            for (int c2 = 0; c2 < CS; c2++) {
                s += __expf(v[c2] - m);
                if (c2 == cs) own = v[c2];
            }
            contrib += (m + __logf(s)) - own;
        } else {
            float dx = x - 0.5f, dy = y - 0.5f;
            contrib = 0.5f * (dx * dx + dy * dy + w * w + h * h);
            if (!silent) contrib += 0.5f * conf * conf;
        }
    }

    // block reduction: wave shuffle then cross-wave via LDS
#pragma unroll
    for (int o = 32; o > 0; o >>= 1) contrib += __shfl_down(contrib, o, 64);
    int lane = tid & 63, wid = tid >> 6;
    if (lane == 0) sred[wid] = contrib;
    __syncthreads();
    if (tid == 0) {
        float bsum = sred[0] + sred[1] + sred[2] + sred[3];
        atomicAdd(loss, bsum);
    }
}

// ---------------------------------------------------------------------------
// meta1: enews[c][d] = mean of dw rows with id==c. Grid (20, 4) x 256.
// ---------------------------------------------------------------------------
__global__ __launch_bounds__(256) void meta1_k(const float* __restrict__ dw,
                                               const int* __restrict__ ids,
                                               float* __restrict__ enews) {
    int c = blockIdx.x;
    int d = blockIdx.y * 256 + threadIdx.x;
    float acc = 0.0f;
    int cnt = 0;
    for (int r = 0; r < DWROWS; r++) {
        int idr = ids[r];                 // uniform -> scalar load
        float v = dw[r * DWDIM + d];
        if (idr == c) { acc += v; cnt++; }
    }
    enews[c * DWDIM + d] = acc / fmaxf((float)cnt, 1.0f);
}

// ---------------------------------------------------------------------------
// meta23: blocks 0..63 -> same-term rows (atomicAdd to loss);
//         blocks 64..463 -> 400 pairwise distances into dmat.
// ---------------------------------------------------------------------------
__global__ __launch_bounds__(256) void meta23_k(const float* __restrict__ dw,
                                                const int* __restrict__ ids,
                                                const float* __restrict__ enews,
                                                float* __restrict__ dmat,
                                                float* __restrict__ loss) {
    __shared__ float sred[4];
    int tid = threadIdx.x;
    float s = 0.0f;
    if (blockIdx.x < DWROWS) {
        int r = blockIdx.x;
        int idr = ids[r];
#pragma unroll
        for (int c = 0; c < 4; c++) {
            int d = tid + c * 256;
            float df = dw[r * DWDIM + d] - enews[idr * DWDIM + d];
            s += df * df;
        }
    } else {
        int p = blockIdx.x - DWROWS;
        int pi = p / NMETA;
        int pj = p - pi * NMETA;
        if (pi != pj) {
#pragma unroll
            for (int c = 0; c < 4; c++) {
                int d = tid + c * 256;
                float df = enews[pi * DWDIM + d] - enews[pj * DWDIM + d];
                s += df * df;
            }
        }
    }
#pragma unroll
    for (int o = 32; o > 0; o >>= 1) s += __shfl_down(s, o, 64);
    int lane = tid & 63, wid = tid >> 6;
    if (lane == 0) sred[wid] = s;
    __syncthreads();
    if (tid == 0) {
        float tot = sred[0] + sred[1] + sred[2] + sred[3];
        if (blockIdx.x < DWROWS) atomicAdd(loss, tot);
        else dmat[blockIdx.x - DWROWS] = tot;
    }
}

// ---------------------------------------------------------------------------
// meta4: dmin over valid pairs, subtract from loss. 1 block x 64.
// ---------------------------------------------------------------------------
__global__ __launch_bounds__(64) void meta4_k(const int* __restrict__ ids,
                                              const float* __restrict__ dmat,
                                              float* __restrict__ loss) {
    __shared__ int scnt[NMETA];
    int t = threadIdx.x;
    if (t < NMETA) {
        int c = 0;
        for (int r = 0; r < DWROWS; r++) c += (ids[r] == t) ? 1 : 0;
        scnt[t] = c;
    }
    __syncthreads();
    float dd = 0.0f;
    if (t < NMETA && scnt[t] > 0) {
        float dmin = INFINITY;
        bool any = false;
        for (int j = 0; j < NMETA; j++) {
            if (j != t && scnt[j] > 0) {
                any = true;
                dmin = fminf(dmin, dmat[t * NMETA + j]);
            }
        }
        dd = any ? dmin : 0.0f;
    }
#pragma unroll
    for (int o = 32; o > 0; o >>= 1) dd += __shfl_down(dd, o, 64);
    if (t == 0) atomicAdd(loss, -dd);
}

// ---------------------------------------------------------------------------
extern "C" void kernel_launch(void* const* d_in, const int* in_sizes, int n_in,
                              void* d_out, int out_size, void* d_ws, size_t ws_size,
                              hipStream_t stream) {
    const float* output = (const float*)d_in[0];   // (320, 30, 26, 26)
    const float* target = (const float*)d_in[1];   // (16, 20, 250) == (320, 50, 5)
    const float* dw     = (const float*)d_in[2];   // (1, 64, 1024)
    const int*   ids    = (const int*)d_in[3];     // (64,)
    float* loss = (float*)d_out;

    float* enews = (float*)d_ws;                                   // 80 KB
    float* dmat  = (float*)((char*)d_ws + NMETA * DWDIM * sizeof(float)); // 1.6 KB

    hipMemsetAsync(loss, 0, sizeof(float), stream);
    dim3 grid((KTOT + 255) / 256, NB);
    main_k<<<grid, 256, 0, stream>>>(output, target, loss);
    dim3 g1(NMETA, DWDIM / 256);
    meta1_k<<<g1, 256, 0, stream>>>(dw, ids, enews);
    meta23_k<<<DWROWS + NMETA * NMETA, 256, 0, stream>>>(dw, ids, enews, dmat, loss);
    meta4_k<<<1, 64, 0, stream>>>(ids, dmat, loss);
}